// Round 8
// baseline (1567.664 us; speedup 1.0000x reference)
//
#include <hip/hip_runtime.h>
#include <hip/hip_bf16.h>

typedef short s16x8 __attribute__((ext_vector_type(8)));
typedef float f32x4 __attribute__((ext_vector_type(4)));

// ---------- helpers ----------
__device__ __forceinline__ unsigned short f2bf(float f) {
  unsigned u = __float_as_uint(f);
  u += 0x7fffu + ((u >> 16) & 1u);   // round-to-nearest-even
  return (unsigned short)(u >> 16);
}

__device__ __forceinline__ unsigned cvtpk(float a, float b) {
  unsigned r;  // {lo16: bf16(a), hi16: bf16(b)} — RNE, matches f2bf bit-exact
  asm("v_cvt_pk_bf16_f32 %0, %1, %2" : "=v"(r) : "v"(a), "v"(b));
  return r;
}

__device__ __forceinline__ void gload16(const void* g, void* l) {
  __builtin_amdgcn_global_load_lds(
      (const __attribute__((address_space(1))) unsigned int*)g,
      (__attribute__((address_space(3))) unsigned int*)l,
      16, 0, 0);
}

// ---------- kernel 1: blockwise FWHT of W rows, scale 1/32, cast bf16 ----------
// (x is no longer pre-cast: the GEMM stages x f32 -> bf16 in-register.)
__global__ void __launch_bounds__(256) k_pre(const float* __restrict__ W,
                                             unsigned short* __restrict__ Wh) {
  __shared__ float s[1024];
  const size_t base = (size_t)blockIdx.x * 1024;
  const int t = threadIdx.x;

  float4 v = reinterpret_cast<const float4*>(W + base)[t];
  s[4 * t + 0] = v.x;
  s[4 * t + 1] = v.y;
  s[4 * t + 2] = v.z;
  s[4 * t + 3] = v.w;

#pragma unroll
  for (int h = 1; h < 1024; h <<= 1) {
    __syncthreads();
#pragma unroll
    for (int pp = 0; pp < 2; ++pp) {
      int p = t + pp * 256;
      int i = ((p / h) * (h << 1)) + (p % h);
      float a = s[i], b = s[i + h];
      s[i] = a + b;
      s[i + h] = a - b;
    }
  }
  __syncthreads();

  const float sc = 0.03125f;  // 1/sqrt(1024)
  ushort4 o;
  o.x = f2bf(s[4 * t + 0] * sc);
  o.y = f2bf(s[4 * t + 1] * sc);
  o.z = f2bf(s[4 * t + 2] * sc);
  o.w = f2bf(s[4 * t + 3] * sc);
  reinterpret_cast<ushort4*>(Wh + base)[t] = o;
}

// ---------- kernel 2: 256x256 GEMM, R4 schedule; A staged from x f32 ----------
// A-source: x [M][K] f32 (cast in-register). B: Wh [N][K] bf16. C: [M][N] f32.
// 8 waves (2M x 4N), BK=64. LDS: A 3x32KB (triple buffer) + B 2x32KB = 160KB.
// R4 sync skeleton unchanged (best measured: 237.6us, MfmaUtil 52%, 0 confl).
// A staging replaced: DMA -> {issue 8x global_load_dwordx4(f32) at ph1(t) for
// tile t+3} ... {counted vmcnt; 16x cvt_pk; 4x ds_write_b128 at ph2(t) for
// tile t+2}. Same LDS layout (linear dest slot tid*16, pre-swizzled source
// chunk ck) -> read side identical. Two named A-reg sets (static indexing),
// pairwise-unrolled t-loop.
// vmcnt ledger (verified): outstanding order at ph2(t): [Aregs(t+2):8,
// B(t+1):4, Aregs(t+3):8] -> vmcnt(12); at ph4(t): [B(t+1):4, Aregs(t+3):8,
// B(t+2):4] -> vmcnt(12). Tails: ph2(nt-3)=4, ph4(nt-3)=4, ph4(nt-2)=0.
// ds_write visibility: explicit lgkmcnt(0) before ph2 barrier.

#define STAGE_HALF(gbase, halfRow, koff, ldsDst)                             \
  do {                                                                       \
    gload16(gbase + (size_t)(halfRow)*K + (koff), (ldsDst) + tid * 16);      \
    gload16(gbase + (size_t)((halfRow) + 64)*K + (koff),                     \
            (ldsDst) + 8192 + tid * 16);                                     \
  } while (0)

// issue 8 f32x4 loads covering the full 256-row A tile at k-offset koff
#define ISSUE_A(S, koff)                                                     \
  do { _Pragma("unroll")                                                     \
    for (int L = 0; L < 4; ++L) {                                            \
      const float* p = gAx + (size_t)(L * 64) * K + (koff);                  \
      S[2 * L]     = *(const float4*)(p);                                    \
      S[2 * L + 1] = *(const float4*)(p + 4);                                \
    } } while (0)

// pack 32 f32 -> 32 bf16, write 4x16B to the A buffer (linear dest = tid*16)
#define WRITE_A(S, dst)                                                      \
  do { _Pragma("unroll")                                                     \
    for (int L = 0; L < 4; ++L) {                                            \
      uint4 w;                                                               \
      w.x = cvtpk(S[2*L].x,   S[2*L].y);                                     \
      w.y = cvtpk(S[2*L].z,   S[2*L].w);                                     \
      w.z = cvtpk(S[2*L+1].x, S[2*L+1].y);                                   \
      w.w = cvtpk(S[2*L+1].z, S[2*L+1].w);                                   \
      *(uint4*)((dst) + L * 8192 + tid * 16) = w;                            \
    } } while (0)

#define RD_AF0(bufp)                                                         \
  do { _Pragma("unroll")                                                     \
    for (int i = 0; i < 4; ++i) {                                            \
      af0[i][0] = *(const s16x8*)((bufp) + aoff0 + i * 2048);                \
      af0[i][1] = *(const s16x8*)((bufp) + aoff1 + i * 2048);                \
    } } while (0)

#define RD_AF1(bufp)                                                         \
  do { _Pragma("unroll")                                                     \
    for (int i = 0; i < 4; ++i) {                                            \
      af1[i][0] = *(const s16x8*)((bufp) + aoff0 + 8192 + i * 2048);         \
      af1[i][1] = *(const s16x8*)((bufp) + aoff1 + 8192 + i * 2048);         \
    } } while (0)

#define RD_BF0(bufp)                                                         \
  do { _Pragma("unroll")                                                     \
    for (int j2 = 0; j2 < 2; ++j2) {                                         \
      bf0[j2][0] = *(const s16x8*)((bufp) + boff0 + j2 * 2048);              \
      bf0[j2][1] = *(const s16x8*)((bufp) + boff1 + j2 * 2048);              \
    } } while (0)

#define RD_BF1(bufp)                                                         \
  do { _Pragma("unroll")                                                     \
    for (int j2 = 0; j2 < 2; ++j2) {                                         \
      bf1[j2][0] = *(const s16x8*)((bufp) + boff0 + 4096 + j2 * 2048);       \
      bf1[j2][1] = *(const s16x8*)((bufp) + boff1 + 4096 + j2 * 2048);       \
    } } while (0)

#define MFMA_Q(msel, nsel, AF, BF)                                           \
  do {                                                                       \
    __builtin_amdgcn_s_setprio(1);                                           \
    _Pragma("unroll")                                                        \
    for (int kk = 0; kk < 2; ++kk) {                                         \
      _Pragma("unroll")                                                      \
      for (int i = 0; i < 4; ++i) {                                          \
        _Pragma("unroll")                                                    \
        for (int j2 = 0; j2 < 2; ++j2) {                                     \
          acc[(msel)*4 + i][(nsel)*2 + j2] =                                 \
            __builtin_amdgcn_mfma_f32_16x16x32_bf16(                         \
              AF[i][kk], BF[j2][kk], acc[(msel)*4 + i][(nsel)*2 + j2],       \
              0, 0, 0);                                                      \
        }                                                                    \
      }                                                                      \
    }                                                                        \
    __builtin_amdgcn_s_setprio(0);                                           \
  } while (0)

#define BAR() __builtin_amdgcn_s_barrier()

#define GEMM_ITER(T, CS, IS)                                                 \
do {                                                                         \
  const char* bA  = LDS + am * 32768;                                        \
  const char* bAn = LDS + an * 32768;                                        \
  char*       bAs = LDS + an2 * 32768;                                       \
  const char* bB  = LDS + 98304 + (((T) & 1) << 15);                         \
  const char* bBn = LDS + 98304 + ((((T) + 1) & 1) << 15);                   \
  char*       bBs = (char*)bB;                                               \
  const int koff2 = ((T) + 2) << 6;                                          \
  /* ph1: rd bf1+af1(t); issue A-regs(t+3); BAR; q(0,0) */                   \
  RD_BF1(bB);                                                                \
  RD_AF1(bA);                                                                \
  if ((T) + 3 < nt) ISSUE_A(IS, ((T) + 3) << 6);                             \
  BAR();                                                                     \
  MFMA_Q(0, 0, af0, bf0);                                                    \
  /* ph2: cvt+write A(t+2); BAR; q(0,1) */                                   \
  if ((T) + 2 < nt) {                                                        \
    if ((T) + 3 < nt) {                                                      \
      asm volatile("s_waitcnt vmcnt(12)" ::: "memory");                      \
    } else {                                                                 \
      asm volatile("s_waitcnt vmcnt(4)" ::: "memory");                       \
    }                                                                        \
    WRITE_A(CS, bAs);                                                        \
    asm volatile("s_waitcnt lgkmcnt(0)" ::: "memory");                       \
  }                                                                          \
  BAR();                                                                     \
  MFMA_Q(0, 1, af0, bf1);                                                    \
  /* ph3: stage B(t+2) rows 0-127; BAR; q(1,0) */                            \
  if ((T) + 2 < nt) STAGE_HALF(gBbase, 0, koff2, bBs);                       \
  BAR();                                                                     \
  MFMA_Q(1, 0, af1, bf0);                                                    \
  /* ph4: stage B(t+2) rows 128-255; counted vmcnt; BAR; rd t+1; q(1,1) */   \
  if ((T) + 2 < nt) STAGE_HALF(gBbase, 128, koff2, bBs + 16384);             \
  if ((T) < nt - 3) {                                                        \
    asm volatile("s_waitcnt vmcnt(12)" ::: "memory");                        \
  } else if ((T) == nt - 3) {                                                \
    asm volatile("s_waitcnt vmcnt(4)" ::: "memory");                         \
  } else if ((T) == nt - 2) {                                                \
    asm volatile("s_waitcnt vmcnt(0)" ::: "memory");                         \
  }                                                                          \
  BAR();                                                                     \
  if ((T) + 1 < nt) {                                                        \
    RD_AF0(bAn);                                                             \
    RD_BF0(bBn);                                                             \
  }                                                                          \
  MFMA_Q(1, 1, af1, bf1);                                                    \
  const int tmp = am; am = an; an = an2; an2 = tmp;                          \
} while (0)

__global__ void __launch_bounds__(512, 2) k_gemm256(
    const float* __restrict__ X, const unsigned short* __restrict__ B,
    const float* __restrict__ bias, float* __restrict__ C,
    int M, int N, int K) {
  __shared__ char LDS[163840];   // A: 3 x 32KB @ 0/32768/65536; B: 2 x 32KB @ 98304/131072

  const int tid = threadIdx.x;
  const int lane = tid & 63;
  const int wid = tid >> 6;
  const int wm = wid >> 2;     // 0..1
  const int wn = wid & 3;      // 0..3
  const int fr = lane & 15;
  const int fq = lane >> 4;

  // XCD-aware bijective swizzle (grid = 512, divisible by 8)
  const int nbn = N >> 8;
  const int cpx = gridDim.x >> 3;
  const int swz = (blockIdx.x & 7) * cpx + (blockIdx.x >> 3);
  const int bm = swz / nbn, bn = swz % nbn;

  // ---- staging addressing (linear LDS dest, pre-swizzled global source) ----
  const int r0 = tid >> 3;
  const int ck = (tid & 7) ^ (r0 & 7);
  const float*          gAx   = X + (size_t)(bm * 256 + r0) * K + ck * 8;
  const unsigned short* gBbase = B + (size_t)(bn * 256 + r0) * K + ck * 8;

  // ---- fragment read offsets, local to a 32KB tile (0-conflict pattern) ----
  const int cs0 = ((fq ^ (fr & 7)) << 4);        // kk=0 chunk byte offset
  const int cs1 = (((fq + 4) ^ (fr & 7)) << 4);  // kk=1
  const int aoff0 = wm * 16384 + fr * 128 + cs0;
  const int aoff1 = wm * 16384 + fr * 128 + cs1;
  const int bbase0 = (wn >> 1) * 16384 + (wn & 1) * 8192 + fr * 128;
  const int boff0 = bbase0 + cs0;
  const int boff1 = bbase0 + cs1;

  f32x4 acc[8][4];
#pragma unroll
  for (int m = 0; m < 8; ++m)
#pragma unroll
    for (int n = 0; n < 4; ++n)
      acc[m][n] = (f32x4){0.f, 0.f, 0.f, 0.f};

  s16x8 af0[4][2], af1[4][2], bf0[2][2], bf1[2][2];
  float4 arA[8], arB[8];   // two named A-reg sets (static indexing, rule #20)

  // ---- prologue ----
  ISSUE_A(arA, 0);                                    // A(0) f32 regs   [vm 8]
  ISSUE_A(arB, 64);                                   // A(1) f32 regs   [vm 16]
  STAGE_HALF(gBbase, 0,   0, LDS + 98304);            // B(0) rows 0-127 [vm 18]
  STAGE_HALF(gBbase, 128, 0, LDS + 98304 + 16384);    // B(0) rows 128-255 [vm 20]
  asm volatile("s_waitcnt vmcnt(12)" ::: "memory");   // A(0) regs landed
  WRITE_A(arA, LDS);                                  // A(0) -> buf0
  asm volatile("s_waitcnt vmcnt(4)" ::: "memory");    // A(1) regs landed
  WRITE_A(arB, LDS + 32768);                          // A(1) -> buf1
  ISSUE_A(arA, 128);                                  // A(2) f32 regs   [vm B0:4+A2:8]
  STAGE_HALF(gBbase, 0,   64, LDS + 131072);          // B(1)
  STAGE_HALF(gBbase, 128, 64, LDS + 131072 + 16384);  // [vm 16]
  asm volatile("s_waitcnt vmcnt(12)" ::: "memory");   // B(0) landed (left A2:8,B1:4)
  asm volatile("s_waitcnt lgkmcnt(0)" ::: "memory");  // A writes visible
  BAR();
  RD_AF0(LDS);
  RD_BF0(LDS + 98304);

  const int nt = K >> 6;  // 64 (even)
  int am = 0, an = 1, an2 = 2;   // A buffer rotation (t, t+1, t+2) mod 3
  for (int t = 0; t < nt; t += 2) {
    GEMM_ITER(t,     arA, arB);   // consume A(t+2)=arA, issue A(t+3)->arB
    GEMM_ITER(t + 1, arB, arA);   // consume A(t+3)=arB, issue A(t+4)->arA
  }

  // ---- epilogue: C = acc + bias ----
  // C/D layout (16x16): col = lane&15, row = (lane>>4)*4 + reg  [m89/m91]
  const int row0 = bm * 256 + wm * 128;
  const int col0 = bn * 256 + wn * 64;
  float bv[4];
#pragma unroll
  for (int nf = 0; nf < 4; ++nf) bv[nf] = bias[col0 + nf * 16 + fr];

#pragma unroll
  for (int mf = 0; mf < 8; ++mf) {
#pragma unroll
    for (int nf = 0; nf < 4; ++nf) {
#pragma unroll
      for (int i = 0; i < 4; ++i) {
        const int r = row0 + mf * 16 + fq * 4 + i;
        const int c = col0 + nf * 16 + fr;
        C[(size_t)r * N + c] = acc[mf][nf][i] + bv[nf];
      }
    }
  }
}

// ---------- launcher ----------
extern "C" void kernel_launch(void* const* d_in, const int* in_sizes, int n_in,
                              void* d_out, int out_size, void* d_ws, size_t ws_size,
                              hipStream_t stream) {
  const float* x = (const float*)d_in[0];
  const float* W = (const float*)d_in[1];
  const float* b = (const float*)d_in[2];
  float* out = (float*)d_out;

  const int N = in_sizes[2];                 // 4096 (D_OUT)
  const int K = in_sizes[1] / N;             // 4096 (D_IN)
  const int M = in_sizes[0] / K;             // 8192 (B*S)

  unsigned short* Wh = (unsigned short*)d_ws;              // N*K bf16

  const int nblk_w = (int)(((size_t)N * K) / 1024);        // 16384
  k_pre<<<nblk_w, 256, 0, stream>>>(W, Wh);

  const int grid = (M / 256) * (N / 256);    // 512
  k_gemm256<<<grid, 512, 0, stream>>>(x, Wh, b, out, M, N, K);
}

// Round 9
// 279.324 us; speedup vs baseline: 5.6123x; 5.6123x over previous
//
#include <hip/hip_runtime.h>
#include <hip/hip_bf16.h>

typedef short s16x8 __attribute__((ext_vector_type(8)));
typedef float f32x4 __attribute__((ext_vector_type(4)));

// ---------- helpers ----------
__device__ __forceinline__ unsigned short f2bf(float f) {
  unsigned u = __float_as_uint(f);
  u += 0x7fffu + ((u >> 16) & 1u);   // round-to-nearest-even
  return (unsigned short)(u >> 16);
}

__device__ __forceinline__ void gload16(const void* g, void* l) {
  __builtin_amdgcn_global_load_lds(
      (const __attribute__((address_space(1))) unsigned int*)g,
      (__attribute__((address_space(3))) unsigned int*)l,
      16, 0, 0);
}

// ---------- kernel 1: fused preprocessing ----------
// blocks [0, nblk_w): blockwise FWHT of W rows, scale 1/32, cast bf16
// blocks [nblk_w, gridDim.x): grid-stride cast x f32 -> bf16
__global__ void __launch_bounds__(256) k_pre(const float* __restrict__ W,
                                             unsigned short* __restrict__ Wh,
                                             const float* __restrict__ x,
                                             unsigned short* __restrict__ xb,
                                             int nblk_w, long n4) {
  __shared__ float s[1024];
  const int t = threadIdx.x;

  if (blockIdx.x < nblk_w) {
    const size_t base = (size_t)blockIdx.x * 1024;

    float4 v = reinterpret_cast<const float4*>(W + base)[t];
    s[4 * t + 0] = v.x;
    s[4 * t + 1] = v.y;
    s[4 * t + 2] = v.z;
    s[4 * t + 3] = v.w;

#pragma unroll
    for (int h = 1; h < 1024; h <<= 1) {
      __syncthreads();
#pragma unroll
      for (int pp = 0; pp < 2; ++pp) {
        int p = t + pp * 256;
        int i = ((p / h) * (h << 1)) + (p % h);
        float a = s[i], b = s[i + h];
        s[i] = a + b;
        s[i + h] = a - b;
      }
    }
    __syncthreads();

    const float sc = 0.03125f;  // 1/sqrt(1024)
    ushort4 o;
    o.x = f2bf(s[4 * t + 0] * sc);
    o.y = f2bf(s[4 * t + 1] * sc);
    o.z = f2bf(s[4 * t + 2] * sc);
    o.w = f2bf(s[4 * t + 3] * sc);
    reinterpret_cast<ushort4*>(Wh + base)[t] = o;
  } else {
    long i = (long)(blockIdx.x - nblk_w) * 256 + t;
    const long stride = (long)(gridDim.x - nblk_w) * 256;
    for (; i < n4; i += stride) {
      float4 v = reinterpret_cast<const float4*>(x)[i];
      ushort4 o;
      o.x = f2bf(v.x);
      o.y = f2bf(v.y);
      o.z = f2bf(v.z);
      o.w = f2bf(v.w);
      reinterpret_cast<ushort4*>(xb)[i] = o;
    }
  }
}

// ---------- kernel 2: 256x256 bf16 GEMM, R4 schedule + A triple-buffer ----------
// EXACT best-measured structure (237.6 us GEMM, MfmaUtil 52%, 0 conflicts).
// A: [M][K] bf16, B: [N][K] bf16, C: [M][N] f32.
// 8 waves (2M x 4N), BK=64. LDS: A 3x32KB (triple buffer) + B 2x32KB = 160KB.
// A(t+2) staged ph1/ph2, B(t+2) staged ph3/ph4, counted vmcnt(8) once per
// K-tile, chunk-XOR swizzle (0-conflict measured), setprio around MFMA.
// Measured neighborhood (all worse — do not regress to): 4/8/8/4 read spread
// = 244.6us; 2-BAR/phase = 266; 2-phase merge = 273; 32x32 MFMA = 274
// (4-way LDS conflict, swizzle-invariant); 128^2 tile = ~330 (FETCH 3.5x);
// reg-staged f32 A = 1564 (VGPR cap 128 under launch_bounds -> scratch spill).

#define STAGE_HALF(gbase, halfRow, koff, ldsDst)                             \
  do {                                                                       \
    gload16(gbase + (size_t)(halfRow)*K + (koff), (ldsDst) + tid * 16);      \
    gload16(gbase + (size_t)((halfRow) + 64)*K + (koff),                     \
            (ldsDst) + 8192 + tid * 16);                                     \
  } while (0)

#define RD_AF0(bufp)                                                         \
  do { _Pragma("unroll")                                                     \
    for (int i = 0; i < 4; ++i) {                                            \
      af0[i][0] = *(const s16x8*)((bufp) + aoff0 + i * 2048);                \
      af0[i][1] = *(const s16x8*)((bufp) + aoff1 + i * 2048);                \
    } } while (0)

#define RD_AF1(bufp)                                                         \
  do { _Pragma("unroll")                                                     \
    for (int i = 0; i < 4; ++i) {                                            \
      af1[i][0] = *(const s16x8*)((bufp) + aoff0 + 8192 + i * 2048);         \
      af1[i][1] = *(const s16x8*)((bufp) + aoff1 + 8192 + i * 2048);         \
    } } while (0)

#define RD_BF0(bufp)                                                         \
  do { _Pragma("unroll")                                                     \
    for (int j2 = 0; j2 < 2; ++j2) {                                         \
      bf0[j2][0] = *(const s16x8*)((bufp) + boff0 + j2 * 2048);              \
      bf0[j2][1] = *(const s16x8*)((bufp) + boff1 + j2 * 2048);              \
    } } while (0)

#define RD_BF1(bufp)                                                         \
  do { _Pragma("unroll")                                                     \
    for (int j2 = 0; j2 < 2; ++j2) {                                         \
      bf1[j2][0] = *(const s16x8*)((bufp) + boff0 + 4096 + j2 * 2048);       \
      bf1[j2][1] = *(const s16x8*)((bufp) + boff1 + 4096 + j2 * 2048);       \
    } } while (0)

#define MFMA_Q(msel, nsel, AF, BF)                                           \
  do {                                                                       \
    __builtin_amdgcn_s_setprio(1);                                           \
    _Pragma("unroll")                                                        \
    for (int kk = 0; kk < 2; ++kk) {                                         \
      _Pragma("unroll")                                                      \
      for (int i = 0; i < 4; ++i) {                                          \
        _Pragma("unroll")                                                    \
        for (int j2 = 0; j2 < 2; ++j2) {                                     \
          acc[(msel)*4 + i][(nsel)*2 + j2] =                                 \
            __builtin_amdgcn_mfma_f32_16x16x32_bf16(                         \
              AF[i][kk], BF[j2][kk], acc[(msel)*4 + i][(nsel)*2 + j2],       \
              0, 0, 0);                                                      \
        }                                                                    \
      }                                                                      \
    }                                                                        \
    __builtin_amdgcn_s_setprio(0);                                           \
  } while (0)

#define BAR() __builtin_amdgcn_s_barrier()

__global__ void __launch_bounds__(512, 2) k_gemm256(
    const unsigned short* __restrict__ A, const unsigned short* __restrict__ B,
    const float* __restrict__ bias, float* __restrict__ C,
    int M, int N, int K) {
  __shared__ char LDS[163840];   // A: 3 x 32KB @ 0/32768/65536; B: 2 x 32KB @ 98304/131072

  const int tid = threadIdx.x;
  const int lane = tid & 63;
  const int wid = tid >> 6;
  const int wm = wid >> 2;     // 0..1
  const int wn = wid & 3;      // 0..3
  const int fr = lane & 15;
  const int fq = lane >> 4;

  // XCD-aware bijective swizzle (grid = 512, divisible by 8)
  const int nbn = N >> 8;
  const int cpx = gridDim.x >> 3;
  const int swz = (blockIdx.x & 7) * cpx + (blockIdx.x >> 3);
  const int bm = swz / nbn, bn = swz % nbn;

  // ---- staging addressing (linear LDS dest, pre-swizzled global source) ----
  const int r0 = tid >> 3;
  const int ck = (tid & 7) ^ (r0 & 7);
  const unsigned short* gAbase = A + (size_t)(bm * 256 + r0) * K + ck * 8;
  const unsigned short* gBbase = B + (size_t)(bn * 256 + r0) * K + ck * 8;

  // ---- fragment read offsets, local to a 32KB tile (0-conflict pattern) ----
  const int cs0 = ((fq ^ (fr & 7)) << 4);        // kk=0 chunk byte offset
  const int cs1 = (((fq + 4) ^ (fr & 7)) << 4);  // kk=1
  const int aoff0 = wm * 16384 + fr * 128 + cs0;
  const int aoff1 = wm * 16384 + fr * 128 + cs1;
  const int bbase0 = (wn >> 1) * 16384 + (wn & 1) * 8192 + fr * 128;
  const int boff0 = bbase0 + cs0;
  const int boff1 = bbase0 + cs1;

  f32x4 acc[8][4];
#pragma unroll
  for (int m = 0; m < 8; ++m)
#pragma unroll
    for (int n = 0; n < 4; ++n)
      acc[m][n] = (f32x4){0.f, 0.f, 0.f, 0.f};

  s16x8 af0[4][2], af1[4][2], bf0[2][2], bf1[2][2];

  // ---- prologue: A(0)->bufA0, B(0)->bufB0, A(1)->bufA1, B(1)->bufB1 ----
  STAGE_HALF(gAbase, 0,   0, LDS);                    // A(0) rows 0-127
  STAGE_HALF(gAbase, 128, 0, LDS + 16384);            // A(0) rows 128-255
  STAGE_HALF(gBbase, 0,   0, LDS + 98304);            // B(0) rows 0-127
  STAGE_HALF(gBbase, 128, 0, LDS + 98304 + 16384);    // B(0) rows 128-255
  STAGE_HALF(gAbase, 0,   64, LDS + 32768);           // A(1)
  STAGE_HALF(gAbase, 128, 64, LDS + 32768 + 16384);
  STAGE_HALF(gBbase, 0,   64, LDS + 131072);          // B(1)
  STAGE_HALF(gBbase, 128, 64, LDS + 131072 + 16384);
  asm volatile("s_waitcnt vmcnt(8)" ::: "memory");    // A(0),B(0) landed
  BAR();
  RD_AF0(LDS);
  RD_BF0(LDS + 98304);

  const int nt = K >> 6;  // 64
  int am = 0, an = 1, an2 = 2;   // A buffer rotation (t, t+1, t+2) mod 3
  for (int t = 0; t < nt; ++t) {
    const char* bA  = LDS + am * 32768;
    const char* bAn = LDS + an * 32768;
    char*       bAs = LDS + an2 * 32768;                    // A(t+2) dest
    const char* bB  = LDS + 98304 + ((t & 1) << 15);
    const char* bBn = LDS + 98304 + (((t + 1) & 1) << 15);
    char*       bBs = (char*)bB;                            // B(t+2) dest (same parity)
    const int koff2 = (t + 2) << 6;

    // ---- ph1: reads bf1+af1 (12); stage A(t+2) rows 0-127; BAR; q(0,0)
    RD_BF1(bB);
    RD_AF1(bA);
    if (t + 2 < nt) STAGE_HALF(gAbase, 0, koff2, bAs);
    BAR();
    MFMA_Q(0, 0, af0, bf0);

    // ---- ph2: stage A(t+2) rows 128-255; BAR; q(0,1)
    if (t + 2 < nt) STAGE_HALF(gAbase, 128, koff2, bAs + 16384);
    BAR();
    MFMA_Q(0, 1, af0, bf1);

    // ---- ph3: stage B(t+2) rows 0-127 (bf0/bf1(t) reads drained >=1 BAR ago);
    //      BAR; q(1,0)
    if (t + 2 < nt) STAGE_HALF(gBbase, 0, koff2, bBs);
    BAR();
    MFMA_Q(1, 0, af1, bf0);

    // ---- ph4: stage B(t+2) rows 128-255; counted vmcnt; BAR;
    //      next-tile af0/bf0 reads; q(1,1)
    if (t + 2 < nt) STAGE_HALF(gBbase, 128, koff2, bBs + 16384);
    if (t < nt - 2) {
      asm volatile("s_waitcnt vmcnt(8)" ::: "memory");  // A(t+1),B(t+1) landed
    } else if (t == nt - 2) {
      asm volatile("s_waitcnt vmcnt(0)" ::: "memory");  // tail drain
    }
    BAR();
    if (t + 1 < nt) {
      RD_AF0(bAn);
      RD_BF0(bBn);
    }
    MFMA_Q(1, 1, af1, bf1);

    // rotate A buffers
    const int tmp = am;
    am = an; an = an2; an2 = tmp;
  }

  // ---- epilogue: C = acc + bias ----
  // C/D layout (16x16): col = lane&15, row = (lane>>4)*4 + reg  [m89/m91]
  const int row0 = bm * 256 + wm * 128;
  const int col0 = bn * 256 + wn * 64;
  float bv[4];
#pragma unroll
  for (int nf = 0; nf < 4; ++nf) bv[nf] = bias[col0 + nf * 16 + fr];

#pragma unroll
  for (int mf = 0; mf < 8; ++mf) {
#pragma unroll
    for (int nf = 0; nf < 4; ++nf) {
#pragma unroll
      for (int i = 0; i < 4; ++i) {
        const int r = row0 + mf * 16 + fq * 4 + i;
        const int c = col0 + nf * 16 + fr;
        C[(size_t)r * N + c] = acc[mf][nf][i] + bv[nf];
      }
    }
  }
}

// ---------- launcher ----------
extern "C" void kernel_launch(void* const* d_in, const int* in_sizes, int n_in,
                              void* d_out, int out_size, void* d_ws, size_t ws_size,
                              hipStream_t stream) {
  const float* x = (const float*)d_in[0];
  const float* W = (const float*)d_in[1];
  const float* b = (const float*)d_in[2];
  float* out = (float*)d_out;

  const int N = in_sizes[2];                 // 4096 (D_OUT)
  const int K = in_sizes[1] / N;             // 4096 (D_IN)
  const int M = in_sizes[0] / K;             // 8192 (B*S)

  unsigned short* Xb = (unsigned short*)d_ws;              // M*K bf16
  unsigned short* Wh = Xb + (size_t)M * K;                 // N*K bf16

  const int nblk_w = (int)(((size_t)N * K) / 1024);        // 16384
  const long n4 = ((long)M * K) / 4;
  k_pre<<<nblk_w + 4096, 256, 0, stream>>>(W, Wh, x, Xb, nblk_w, n4);

  const int grid = (M / 256) * (N / 256);    // 512
  k_gemm256<<<grid, 512, 0, stream>>>(Xb, Wh, b, out, M, N, K);
}